// Round 3
// baseline (671.786 us; speedup 1.0000x reference)
//
#include <hip/hip_runtime.h>
#include <math.h>

// Problem dims
#define TSTEPS 4
#define BB 8
#define NN 25000
#define LLD 64
#define DIN 129

// ws offsets (in floats)
#define OFF_WCT   0        // WcT[192][65]  : gi = [r,enc] @ (W_msg@Wi), transposed
#define OFF_WHT   12480    // WhT[192][64]  : Wh transposed
#define OFF_BC    24768    // bc[192] = b_msg@Wi + bi
#define OFF_WVO   24960    // wvo[129] = Wv @ W_out
#define OFF_C0    25089    // c0 = bv@W_out + b_out
#define OFF_MEMA  25600    // memT[64][25000]
#define OFF_MEMB  1625600  // memT[64][25000]
#define OFF_RLAST 3225600  // r_last[25000]
#define OFF_PART  3250600  // partials [8][98][132]
#define NBLK 98
#define PSTRIDE 132

__device__ __forceinline__ float sigm(float x) { return 1.f / (1.f + __expf(-x)); }
__device__ __forceinline__ float tanh_fast(float x) {
  float ax = fabsf(x);
  float e = __expf(-2.f * ax);
  float t = (1.f - e) / (1.f + e);
  return copysignf(t, x);
}

// ---------------- setup: fold weights ----------------
__global__ __launch_bounds__(1024) void k_setup(
    const float* __restrict__ W_msg, const float* __restrict__ Wi,
    const float* __restrict__ bi, const float* __restrict__ b_msg,
    const float* __restrict__ Wh, const float* __restrict__ Wv,
    const float* __restrict__ bv, const float* __restrict__ W_out,
    const float* __restrict__ b_out, float* __restrict__ ws) {
  int id = blockIdx.x * 1024 + threadIdx.x;
  if (id < 12480) {                       // WcT[l][k] = sum_m W_msg[k][m]*Wi[m][l]
    int l = id / 65, k = id % 65;
    float acc = 0.f;
    for (int m = 0; m < 64; m++) acc += W_msg[k * 64 + m] * Wi[m * 192 + l];
    ws[OFF_WCT + id] = acc;
  } else if (id < 24768) {                // WhT[l][k] = Wh[k][l]
    int j = id - 12480;
    int l = j / 64, k = j % 64;
    ws[OFF_WHT + j] = Wh[k * 192 + l];
  } else if (id < 24960) {                // bc[j] = sum_m b_msg[m]*Wi[m][j] + bi[j]
    int jc = id - 24768;
    float acc = bi[jc];
    for (int m = 0; m < 64; m++) acc += b_msg[m] * Wi[m * 192 + jc];
    ws[OFF_BC + jc] = acc;
  } else if (id < 25089) {                // wvo[d] = sum_j Wv[d][j]*W_out[j]
    int d = id - 24960;
    float acc = 0.f;
    for (int j = 0; j < 64; j++) acc += Wv[d * 64 + j] * W_out[j];
    ws[OFF_WVO + d] = acc;
  } else if (id == 25089) {               // c0
    float acc = b_out[0];
    for (int j = 0; j < 64; j++) acc += bv[j] * W_out[j];
    ws[OFF_C0] = acc;
  }
}

// ---------------- GRU update: mem2 = gru([r,enc]@Wc, mem) ----------------
// Block = 512 threads = 8 waves. Wave w handles output dims [w*8, w*8+8).
// Lanes = 64 consecutive n. Weight addresses are wave-uniform -> scalar loads.
__global__ __launch_bounds__(512) void k_gru(
    const float* __restrict__ t_in, const float* __restrict__ raw,
    const float* __restrict__ r_last, const float* __restrict__ w_t,
    const float* __restrict__ b_t, const float* __restrict__ bh,
    const float* __restrict__ wct, const float* __restrict__ wht,
    const float* __restrict__ bc, const float* __restrict__ memPrev,
    float* __restrict__ memNext, int tt) {
  int lane = threadIdx.x & 63;
  int wv = __builtin_amdgcn_readfirstlane(threadIdx.x >> 6);
  int n = blockIdx.x * 64 + lane;
  if (n >= NN) return;

  float tb = t_in[((tt * BB + (BB - 1)) * NN) + n];
  float rn = (tt == 0) ? raw[(BB - 1) * NN + n] : r_last[n];

  float enc[64], mem[64];
#pragma unroll
  for (int k = 0; k < 64; k++) enc[k] = __cosf(tb * w_t[k] + b_t[k]);
#pragma unroll
  for (int k = 0; k < 64; k++) mem[k] = memPrev[k * NN + n];

  for (int li = 0; li < 8; ++li) {
    int l = wv * 8 + li;
    const float* wr = wct + l * 65;
    const float* wz = wct + (l + 64) * 65;
    const float* wn = wct + (l + 128) * 65;
    float ar = bc[l] + rn * wr[0];
    float az = bc[l + 64] + rn * wz[0];
    float an = bc[l + 128] + rn * wn[0];
#pragma unroll
    for (int k = 0; k < 64; k++) {
      ar += enc[k] * wr[k + 1];
      az += enc[k] * wz[k + 1];
      an += enc[k] * wn[k + 1];
    }
    const float* hr_p = wht + l * 64;
    const float* hz_p = wht + (l + 64) * 64;
    const float* hn_p = wht + (l + 128) * 64;
    float hr = bh[l], hz = bh[l + 64], hn = bh[l + 128];
#pragma unroll
    for (int k = 0; k < 64; k++) {
      hr += mem[k] * hr_p[k];
      hz += mem[k] * hz_p[k];
      hn += mem[k] * hn_p[k];
    }
    float rg = sigm(ar + hr);
    float zg = sigm(az + hz);
    float ng = tanh_fast(an + rg * hn);
    float mprev = memPrev[l * NN + n];  // reload to avoid runtime-indexed reg array
    memNext[l * NN + n] = (1.f - zg) * ng + zg * mprev;
  }
}

// ---------------- attention: scores + online-softmax partial hbar ----------------
// grid (NBLK, BB), 256 threads. Each block: one b, 256 n's.
__global__ __launch_bounds__(256) void k_attn(
    const float* __restrict__ t_in, const float* __restrict__ raw,
    const float* __restrict__ r_last, const int* __restrict__ n_mask,
    const int* __restrict__ tar, const float* __restrict__ w_t,
    const float* __restrict__ b_t, const float* __restrict__ Wq,
    const float* __restrict__ bq, const float* __restrict__ Wk,
    const float* __restrict__ bk, const float* __restrict__ mem2,
    float* __restrict__ part, int tt) {
  __shared__ float q_sh[64], th_sh[64], wq_sh[129];
  __shared__ float red[256], e_sh[256], t_sh[256], r_sh[256];
  __shared__ float c_sh;

  int tid = threadIdx.x;
  int b = blockIdx.y;
  int n0 = blockIdx.x * 256;
  int n = n0 + tid;
  int tarn = tar[tt * BB + b];

  // ---- phase Q: q = tar_h @ Wq + bq ; wq = Wk @ q ; c = bk . q ----
  if (tid < 64) th_sh[tid] = mem2[tid * NN + tarn];
  __syncthreads();
  if (tid < 64) {
    float tr = (tt == 0) ? raw[b * NN + tarn] : r_last[tarn];
    float acc = bq[tid] + tr * Wq[tid];
#pragma unroll 8
    for (int k = 0; k < 64; k++) acc += th_sh[k] * Wq[(1 + k) * 64 + tid];
#pragma unroll 8
    for (int l = 0; l < 64; l++) acc += __cosf(b_t[l]) * Wq[(65 + l) * 64 + tid];
    q_sh[tid] = acc;
  }
  __syncthreads();
  if (tid < 129) {
    float acc = 0.f;
#pragma unroll 8
    for (int j = 0; j < 64; j++) acc += Wk[tid * 64 + j] * q_sh[j];
    wq_sh[tid] = acc;
  }
  if (tid == 192) {
    float acc = 0.f;
    for (int j = 0; j < 64; j++) acc += bk[j] * q_sh[j];
    c_sh = acc;
  }
  __syncthreads();

  // ---- phase 1: score for this n ----
  bool valid = (n < NN);
  float tb = 0.f, rn = 0.f, score = -1e30f;
  int mk = 0;
  if (valid) {
    tb = t_in[((tt * BB + b) * NN) + n];
    mk = n_mask[(tt * BB + b) * NN + n];
    rn = (tt == 0) ? raw[b * NN + n] : r_last[n];
    float acc = rn * wq_sh[0];
#pragma unroll 8
    for (int d = 0; d < 64; d++) acc += mem2[d * NN + n] * wq_sh[1 + d];
#pragma unroll 8
    for (int l = 0; l < 64; l++) acc += __cosf(tb * w_t[l] + b_t[l]) * wq_sh[65 + l];
    score = (acc + c_sh) * 0.125f;
  }
  bool act = valid && (mk > 0);

  red[tid] = act ? score : -1e30f;
  __syncthreads();
  for (int s = 128; s > 0; s >>= 1) {
    if (tid < s) red[tid] = fmaxf(red[tid], red[tid + s]);
    __syncthreads();
  }
  float mb = red[0];
  __syncthreads();

  float e = act ? __expf(score - mb) : 0.f;
  red[tid] = e;
  __syncthreads();
  for (int s = 128; s > 0; s >>= 1) {
    if (tid < s) red[tid] += red[tid + s];
    __syncthreads();
  }
  float Sb = red[0];
  __syncthreads();

  e_sh[tid] = e;
  t_sh[tid] = tb;
  r_sh[tid] = rn;
  __syncthreads();

  // ---- phase 2: partial hbar = sum e * h ----
  int lim = min(256, NN - n0);
  int pbase = (b * NBLK + blockIdx.x) * PSTRIDE;
  if (tid < 64) {  // mem dims
    const float* mrow = mem2 + tid * NN + n0;
    float acc = 0.f;
    for (int i = 0; i < lim; i++) acc += e_sh[i] * mrow[i];
    part[pbase + 1 + tid] = acc;
  } else if (tid < 128) {  // enc dims
    int l = tid - 64;
    float wl = w_t[l], bl = b_t[l];
    float acc = 0.f;
    for (int i = 0; i < lim; i++) acc += e_sh[i] * __cosf(t_sh[i] * wl + bl);
    part[pbase + 1 + tid] = acc;  // slot 65+l == 1+tid
  } else if (tid == 128) {  // r dim
    float acc = 0.f;
    for (int i = 0; i < lim; i++) acc += e_sh[i] * r_sh[i];
    part[pbase + 0] = acc;
  } else if (tid == 129) {
    part[pbase + 129] = mb;
  } else if (tid == 130) {
    part[pbase + 130] = Sb;
  }
}

// ---------------- finish: merge partials -> logits; update r state ----------------
__global__ __launch_bounds__(256) void k_finish(
    const float* __restrict__ part, const float* __restrict__ wvo,
    const float* __restrict__ c0p, const int* __restrict__ tar,
    const float* __restrict__ raw, const float* __restrict__ r_label,
    float* __restrict__ r_last, float* __restrict__ out, int tt) {
  __shared__ float red[256], fac[NBLK], hb[129], lg_sh[8];
  int tid = threadIdx.x;

  for (int b = 0; b < BB; b++) {
    const float* pb = part + b * NBLK * PSTRIDE;
    red[tid] = (tid < NBLK) ? pb[tid * PSTRIDE + 129] : -1e30f;
    __syncthreads();
    for (int s = 128; s > 0; s >>= 1) {
      if (tid < s) red[tid] = fmaxf(red[tid], red[tid + s]);
      __syncthreads();
    }
    float mb = red[0];
    __syncthreads();
    if (tid < NBLK) fac[tid] = __expf(pb[tid * PSTRIDE + 129] - mb);
    __syncthreads();
    red[tid] = (tid < NBLK) ? pb[tid * PSTRIDE + 130] * fac[tid] : 0.f;
    __syncthreads();
    for (int s = 128; s > 0; s >>= 1) {
      if (tid < s) red[tid] += red[tid + s];
      __syncthreads();
    }
    float Sb = red[0];
    __syncthreads();
    if (tid < 129) {
      float acc = 0.f;
      for (int j = 0; j < NBLK; j++) acc += pb[j * PSTRIDE + tid] * fac[j];
      hb[tid] = acc * wvo[tid];
    }
    __syncthreads();
    if (tid == 0) {
      float s2 = 0.f;
      for (int d = 0; d < 129; d++) s2 += hb[d];
      float lg = s2 / Sb + c0p[0];
      lg_sh[b] = lg;
      out[tt * BB + b] = lg;
    }
    __syncthreads();
  }

  // r_last update: r_new = 0.5*(r_prev_b7 + rlab)
  for (int n = tid; n < NN; n += 256) {
    float base = (tt == 0) ? raw[(BB - 1) * NN + n] : r_last[n];
    r_last[n] = 0.5f * (base + r_label[((tt * BB + (BB - 1)) * NN) + n]);
  }
  __syncthreads();
  if (tid == 0) {  // tar overwrites, in order (last wins)
    for (int b = 0; b < BB; b++) {
      int nb = tar[tt * BB + b];
      r_last[nb] = 0.5f * (lg_sh[b] + r_label[((tt * BB + (BB - 1)) * NN) + nb]);
    }
  }
}

extern "C" void kernel_launch(void* const* d_in, const int* in_sizes, int n_in,
                              void* d_out, int out_size, void* d_ws, size_t ws_size,
                              hipStream_t stream) {
  const float* raw     = (const float*)d_in[0];
  const float* r_label = (const float*)d_in[1];
  const float* t_in    = (const float*)d_in[2];
  const int*   tar     = (const int*)d_in[4];
  const int*   n_mask  = (const int*)d_in[5];
  const float* w_t     = (const float*)d_in[6];
  const float* b_t     = (const float*)d_in[7];
  const float* W_msg   = (const float*)d_in[8];
  const float* b_msg   = (const float*)d_in[9];
  const float* Wi      = (const float*)d_in[10];
  const float* Wh      = (const float*)d_in[11];
  const float* bi      = (const float*)d_in[12];
  const float* bh      = (const float*)d_in[13];
  const float* Wq      = (const float*)d_in[14];
  const float* bq      = (const float*)d_in[15];
  const float* Wk      = (const float*)d_in[16];
  const float* bk      = (const float*)d_in[17];
  const float* Wv      = (const float*)d_in[18];
  const float* bv      = (const float*)d_in[19];
  const float* W_out   = (const float*)d_in[20];
  const float* b_out   = (const float*)d_in[21];

  float* ws  = (float*)d_ws;
  float* out = (float*)d_out;

  // initial memory state = 0
  hipMemsetAsync(ws + OFF_MEMA, 0, (size_t)64 * NN * sizeof(float), stream);
  k_setup<<<25, 1024, 0, stream>>>(W_msg, Wi, bi, b_msg, Wh, Wv, bv, W_out, b_out, ws);

  for (int tt = 0; tt < TSTEPS; tt++) {
    float* mp = ws + ((tt & 1) ? OFF_MEMB : OFF_MEMA);
    float* mn = ws + ((tt & 1) ? OFF_MEMA : OFF_MEMB);
    k_gru<<<dim3((NN + 63) / 64), dim3(512), 0, stream>>>(
        t_in, raw, ws + OFF_RLAST, w_t, b_t, bh,
        ws + OFF_WCT, ws + OFF_WHT, ws + OFF_BC, mp, mn, tt);
    k_attn<<<dim3(NBLK, BB), 256, 0, stream>>>(
        t_in, raw, ws + OFF_RLAST, n_mask, tar, w_t, b_t,
        Wq, bq, Wk, bk, mn, ws + OFF_PART, tt);
    k_finish<<<1, 256, 0, stream>>>(
        ws + OFF_PART, ws + OFF_WVO, ws + OFF_C0, tar,
        raw, r_label, ws + OFF_RLAST, out, tt);
  }
}

// Round 4
// 351.273 us; speedup vs baseline: 1.9124x; 1.9124x over previous
//
#include <hip/hip_runtime.h>
#include <math.h>

// Problem dims
#define TSTEPS 4
#define BB 8
#define NN 25000
#define LLD 64
#define DIN 129

// ws offsets (in floats)
#define OFF_WC    0        // Wc[65][192] = W_msg @ Wi (row k, col j)
#define OFF_BC    12480    // bc[192] = b_msg@Wi + bi
#define OFF_WVO   12672    // wvo[129] = Wv @ W_out  (dim order: r, mem(64), enc(64))
#define OFF_C0    12801    // c0 = bv@W_out + b_out
#define OFF_WQC   12832    // wq_all [8][132]: wq[129], c at [129]
#define OFF_MEMA  16384    // memT[64][25000]
#define OFF_MEMB  1616384  // memT[64][25000]
#define OFF_RLAST 3216384  // r_last[25000]
#define OFF_PART  3241384  // partials [8][98][132]: slots 0..128 dims, 129 max, 130 sum
#define NBLK 98
#define PSTRIDE 132

__device__ __forceinline__ float sigm(float x) { return 1.f / (1.f + __expf(-x)); }
__device__ __forceinline__ float tanh_fast(float x) {
  float ax = fabsf(x);
  float e = __expf(-2.f * ax);
  float t = (1.f - e) / (1.f + e);
  return copysignf(t, x);
}
__device__ __forceinline__ float wred_max(float v) {
#pragma unroll
  for (int m = 32; m; m >>= 1) v = fmaxf(v, __shfl_xor(v, m));
  return v;
}
__device__ __forceinline__ float wred_sum(float v) {
#pragma unroll
  for (int m = 32; m; m >>= 1) v += __shfl_xor(v, m);
  return v;
}

// ---------------- setup: fold weights ----------------
__global__ __launch_bounds__(1024) void k_setup(
    const float* __restrict__ W_msg, const float* __restrict__ Wi,
    const float* __restrict__ bi, const float* __restrict__ b_msg,
    const float* __restrict__ Wv, const float* __restrict__ bv,
    const float* __restrict__ W_out, const float* __restrict__ b_out,
    float* __restrict__ ws) {
  int id = blockIdx.x * 1024 + threadIdx.x;
  if (id < 12480) {                       // Wc[k][j] = sum_m W_msg[k][m]*Wi[m][j]
    int k = id / 192, j = id % 192;
    float acc = 0.f;
    for (int m = 0; m < 64; m++) acc += W_msg[k * 64 + m] * Wi[m * 192 + j];
    ws[OFF_WC + id] = acc;
  } else if (id < 12672) {                // bc[j]
    int j = id - 12480;
    float acc = bi[j];
    for (int m = 0; m < 64; m++) acc += b_msg[m] * Wi[m * 192 + j];
    ws[OFF_BC + j] = acc;
  } else if (id < 12801) {                // wvo[d]
    int d = id - 12672;
    float acc = 0.f;
    for (int j = 0; j < 64; j++) acc += Wv[d * 64 + j] * W_out[j];
    ws[OFF_WVO + d] = acc;
  } else if (id == 12801) {               // c0
    float acc = b_out[0];
    for (int j = 0; j < 64; j++) acc += bv[j] * W_out[j];
    ws[OFF_C0] = acc;
  }
}

// ---------------- GRU: 8 waves/block, wave owns 8 l's; LDS-staged mem/enc ----------------
__global__ __launch_bounds__(512) void k_gru(
    const float* __restrict__ t_in, const float* __restrict__ raw,
    const float* __restrict__ r_last, const float* __restrict__ w_t,
    const float* __restrict__ b_t, const float* __restrict__ bh,
    const float* __restrict__ wc, const float* __restrict__ wh,
    const float* __restrict__ bc, const float* __restrict__ memPrev,
    float* __restrict__ memNext, int tt) {
  __shared__ float mem_lds[64][64];
  __shared__ float enc_lds[64][64];
  int tid = threadIdx.x;
  int lane = tid & 63;
  int wv = tid >> 6;
  int n = blockIdx.x * 64 + lane;
  int nc = min(n, NN - 1);

  float tb = t_in[(tt * BB + BB - 1) * NN + nc];
  float rn = (tt == 0) ? raw[(BB - 1) * NN + nc] : r_last[nc];

  // stage: wave wv fills k = wv*8 .. wv*8+7 (coalesced global, wave-uniform w_t/b_t)
#pragma unroll
  for (int r = 0; r < 8; r++) {
    int k = wv * 8 + r;
    mem_lds[k][lane] = memPrev[k * NN + nc];
    enc_lds[k][lane] = __cosf(tb * w_t[k] + b_t[k]);
  }
  __syncthreads();

  int jb = __builtin_amdgcn_readfirstlane(wv * 8);
  float aR[8], aZ[8], aN[8], hR[8], hZ[8], hN[8];
#pragma unroll
  for (int li = 0; li < 8; li++) {        // biases + r-term (Wc row 0)
    aR[li] = bc[jb + li]        + rn * wc[jb + li];
    aZ[li] = bc[64 + jb + li]   + rn * wc[64 + jb + li];
    aN[li] = bc[128 + jb + li]  + rn * wc[128 + jb + li];
    hR[li] = bh[jb + li];
    hZ[li] = bh[64 + jb + li];
    hN[li] = bh[128 + jb + li];
  }

#pragma unroll 2
  for (int k = 0; k < 64; k++) {
    float ek = enc_lds[k][lane];
    float mk = mem_lds[k][lane];
    const float* wrow = wc + (k + 1) * 192 + jb;   // wave-uniform rows -> s_load
    const float* hrow = wh + k * 192 + jb;
#pragma unroll
    for (int li = 0; li < 8; li++) {
      aR[li] += ek * wrow[li];
      aZ[li] += ek * wrow[64 + li];
      aN[li] += ek * wrow[128 + li];
      hR[li] += mk * hrow[li];
      hZ[li] += mk * hrow[64 + li];
      hN[li] += mk * hrow[128 + li];
    }
  }

  if (n < NN) {
#pragma unroll
    for (int li = 0; li < 8; li++) {
      int l = jb + li;
      float rg = sigm(aR[li] + hR[li]);
      float zg = sigm(aZ[li] + hZ[li]);
      float ng = tanh_fast(aN[li] + rg * hN[li]);
      memNext[l * NN + n] = (1.f - zg) * ng + zg * mem_lds[l][lane];
    }
  }
}

// ---------------- q-projection: one small block per b ----------------
__global__ __launch_bounds__(192) void k_q(
    const float* __restrict__ raw, const float* __restrict__ r_last,
    const int* __restrict__ tar, const float* __restrict__ b_t,
    const float* __restrict__ Wq, const float* __restrict__ bq,
    const float* __restrict__ Wk, const float* __restrict__ bk,
    const float* __restrict__ mem2, float* __restrict__ wqc, int tt) {
  __shared__ float th_sh[64], q_sh[64];
  int tid = threadIdx.x;
  int b = blockIdx.x;
  int tarn = tar[tt * BB + b];

  if (tid < 64) th_sh[tid] = mem2[tid * NN + tarn];
  __syncthreads();
  if (tid < 64) {
    float tr = (tt == 0) ? raw[b * NN + tarn] : r_last[tarn];
    float acc = bq[tid] + tr * Wq[tid];
#pragma unroll 8
    for (int k = 0; k < 64; k++) acc += th_sh[k] * Wq[(1 + k) * 64 + tid];
#pragma unroll 8
    for (int l = 0; l < 64; l++) acc += __cosf(b_t[l]) * Wq[(65 + l) * 64 + tid];
    q_sh[tid] = acc;
  }
  __syncthreads();
  if (tid < 129) {
    float acc = 0.f;
#pragma unroll 8
    for (int j = 0; j < 64; j++) acc += Wk[tid * 64 + j] * q_sh[j];
    wqc[b * 132 + tid] = acc;
  } else if (tid == 129) {
    float acc = 0.f;
    for (int j = 0; j < 64; j++) acc += bk[j] * q_sh[j];
    wqc[b * 132 + 129] = acc;
  }
}

// ---------------- attention: scores + softmax partials, wave-split phase 2 ----------------
__global__ __launch_bounds__(256) void k_attn(
    const float* __restrict__ t_in, const float* __restrict__ raw,
    const float* __restrict__ r_last, const int* __restrict__ n_mask,
    const float* __restrict__ w_t, const float* __restrict__ b_t,
    const float* __restrict__ wqc, const float* __restrict__ mem2,
    float* __restrict__ part, int tt) {
  __shared__ float wq_lds[132];
  __shared__ float e_sh[256], t_sh[256];
  __shared__ float red4[4], redS[4], redR[4];
  __shared__ float pm[2][64], pe[2][64];

  int tid = threadIdx.x;
  int lane = tid & 63;
  int wvid = tid >> 6;
  int b = blockIdx.y;
  int n0 = blockIdx.x * 256;
  int n = n0 + tid;
  int nc = min(n, NN - 1);
  bool valid = (n < NN);

  if (tid < 132) wq_lds[tid] = wqc[b * 132 + tid];

  float tb = t_in[(tt * BB + b) * NN + nc];
  int mk = n_mask[(tt * BB + b) * NN + nc];
  float rn = (tt == 0) ? raw[b * NN + nc] : r_last[nc];
  __syncthreads();

  // score
  float sc = rn * wq_lds[0];
#pragma unroll 8
  for (int d = 0; d < 64; d++) sc += mem2[d * NN + nc] * wq_lds[1 + d];
#pragma unroll 8
  for (int l = 0; l < 64; l++) sc += __cosf(tb * w_t[l] + b_t[l]) * wq_lds[65 + l];
  float score = (sc + wq_lds[129]) * 0.125f;
  bool act = valid && (mk > 0);

  // block max via wave shuffles
  float mw = wred_max(act ? score : -1e30f);
  if (lane == 0) red4[wvid] = mw;
  __syncthreads();
  float mb = fmaxf(fmaxf(red4[0], red4[1]), fmaxf(red4[2], red4[3]));

  float e = act ? __expf(score - mb) : 0.f;
  float sw = wred_sum(e);
  float sr = wred_sum(e * rn);
  if (lane == 0) { redS[wvid] = sw; redR[wvid] = sr; }
  e_sh[tid] = e;
  t_sh[tid] = tb;
  __syncthreads();
  float Sb = redS[0] + redS[1] + redS[2] + redS[3];
  float Rb = redR[0] + redR[1] + redR[2] + redR[3];

  // phase 2: wave 0/1 -> mem dims (i halves), wave 2/3 -> enc dims
  if (wvid < 2) {
    const float* mrow = mem2 + lane * NN + n0;
    int i0 = wvid * 128;
    float acc = 0.f;
#pragma unroll 4
    for (int i = i0; i < i0 + 128; i++) acc += e_sh[i] * mrow[i];
    pm[wvid][lane] = acc;
  } else {
    float wl = w_t[lane], bl = b_t[lane];
    int i0 = (wvid - 2) * 128;
    float acc = 0.f;
#pragma unroll 4
    for (int i = i0; i < i0 + 128; i++) acc += e_sh[i] * __cosf(t_sh[i] * wl + bl);
    pe[wvid - 2][lane] = acc;
  }
  __syncthreads();

  int pbase = (b * NBLK + blockIdx.x) * PSTRIDE;
  if (tid < 64) part[pbase + 1 + tid] = pm[0][tid] + pm[1][tid];
  else if (tid < 128) part[pbase + 65 + (tid - 64)] = pe[0][tid - 64] + pe[1][tid - 64];
  else if (tid == 128) part[pbase + 0] = Rb;
  else if (tid == 129) part[pbase + 129] = mb;
  else if (tid == 130) part[pbase + 130] = Sb;
}

// ---------------- finish: wave-per-b merge; r_last update ----------------
__global__ __launch_bounds__(512) void k_finish(
    const float* __restrict__ part, const float* __restrict__ wvo,
    const float* __restrict__ c0p, const int* __restrict__ tar,
    const float* __restrict__ raw, const float* __restrict__ r_label,
    float* __restrict__ r_last, float* __restrict__ out, int tt) {
  __shared__ float fac_lds[BB][104];
  __shared__ float lg_sh[BB];
  int tid = threadIdx.x;
  int lane = tid & 63;
  int b = tid >> 6;
  const float* pb = part + b * NBLK * PSTRIDE;

  float m1 = pb[lane * PSTRIDE + 129];
  float m2 = (lane < NBLK - 64) ? pb[(lane + 64) * PSTRIDE + 129] : -1e30f;
  float mb = wred_max(fmaxf(m1, m2));
  float f1 = __expf(m1 - mb);
  float f2 = (lane < NBLK - 64) ? __expf(m2 - mb) : 0.f;
  float sl = pb[lane * PSTRIDE + 130] * f1;
  if (lane < NBLK - 64) sl += pb[(lane + 64) * PSTRIDE + 130] * f2;
  float Sb = wred_sum(sl);
  fac_lds[b][lane] = f1;
  if (lane < NBLK - 64) fac_lds[b][lane + 64] = f2;
  __syncthreads();

  float a1 = 0.f, a2 = 0.f, a3 = 0.f;
  for (int j = 0; j < NBLK; j++) {
    float fj = fac_lds[b][j];
    const float* row = pb + j * PSTRIDE;
    a1 += fj * row[lane];          // slots 0..63
    a2 += fj * row[64 + lane];     // slots 64..127
    a3 += fj * row[128];           // slot 128 (uniform)
  }
  float partl = a1 * wvo[lane] + a2 * wvo[64 + lane] + ((lane == 0) ? a3 * wvo[128] : 0.f);
  float s2 = wred_sum(partl);
  if (lane == 0) {
    float lg = s2 / Sb + c0p[0];
    lg_sh[b] = lg;
    out[tt * BB + b] = lg;
  }
  __syncthreads();

  for (int nn = tid; nn < NN; nn += 512) {
    float base = (tt == 0) ? raw[(BB - 1) * NN + nn] : r_last[nn];
    r_last[nn] = 0.5f * (base + r_label[(tt * BB + BB - 1) * NN + nn]);
  }
  __syncthreads();
  if (tid == 0) {
    for (int bb = 0; bb < BB; bb++) {
      int nb = tar[tt * BB + bb];
      r_last[nb] = 0.5f * (lg_sh[bb] + r_label[(tt * BB + BB - 1) * NN + nb]);
    }
  }
}

extern "C" void kernel_launch(void* const* d_in, const int* in_sizes, int n_in,
                              void* d_out, int out_size, void* d_ws, size_t ws_size,
                              hipStream_t stream) {
  const float* raw     = (const float*)d_in[0];
  const float* r_label = (const float*)d_in[1];
  const float* t_in    = (const float*)d_in[2];
  const int*   tar     = (const int*)d_in[4];
  const int*   n_mask  = (const int*)d_in[5];
  const float* w_t     = (const float*)d_in[6];
  const float* b_t     = (const float*)d_in[7];
  const float* W_msg   = (const float*)d_in[8];
  const float* b_msg   = (const float*)d_in[9];
  const float* Wi      = (const float*)d_in[10];
  const float* Wh      = (const float*)d_in[11];
  const float* bi      = (const float*)d_in[12];
  const float* bh      = (const float*)d_in[13];
  const float* Wq      = (const float*)d_in[14];
  const float* bq      = (const float*)d_in[15];
  const float* Wk      = (const float*)d_in[16];
  const float* bk      = (const float*)d_in[17];
  const float* Wv      = (const float*)d_in[18];
  const float* bv      = (const float*)d_in[19];
  const float* W_out   = (const float*)d_in[20];
  const float* b_out   = (const float*)d_in[21];

  float* ws  = (float*)d_ws;
  float* out = (float*)d_out;

  hipMemsetAsync(ws + OFF_MEMA, 0, (size_t)64 * NN * sizeof(float), stream);
  k_setup<<<13, 1024, 0, stream>>>(W_msg, Wi, bi, b_msg, Wv, bv, W_out, b_out, ws);

  for (int tt = 0; tt < TSTEPS; tt++) {
    float* mp = ws + ((tt & 1) ? OFF_MEMB : OFF_MEMA);
    float* mn = ws + ((tt & 1) ? OFF_MEMA : OFF_MEMB);
    k_gru<<<dim3((NN + 63) / 64), dim3(512), 0, stream>>>(
        t_in, raw, ws + OFF_RLAST, w_t, b_t, bh,
        ws + OFF_WC, Wh, ws + OFF_BC, mp, mn, tt);
    k_q<<<dim3(BB), dim3(192), 0, stream>>>(
        raw, ws + OFF_RLAST, tar, b_t, Wq, bq, Wk, bk, mn, ws + OFF_WQC, tt);
    k_attn<<<dim3(NBLK, BB), dim3(256), 0, stream>>>(
        t_in, raw, ws + OFF_RLAST, n_mask, w_t, b_t,
        ws + OFF_WQC, mn, ws + OFF_PART, tt);
    k_finish<<<1, 512, 0, stream>>>(
        ws + OFF_PART, ws + OFF_WVO, ws + OFF_C0, tar,
        raw, r_label, ws + OFF_RLAST, out, tt);
  }
}

// Round 6
// 264.008 us; speedup vs baseline: 2.5446x; 1.3305x over previous
//
#include <hip/hip_runtime.h>
#include <math.h>

// Problem dims
#define TSTEPS 4
#define BB 8
#define NN 25000
#define LLD 64
#define DIN 129

// ws offsets (in floats)
#define OFF_WC    0        // Wc[65][192] = W_msg @ Wi (row k, col j)
#define OFF_BC    12480    // bc[192] = b_msg@Wi + bi
#define OFF_WVO   12672    // wvo[129] = Wv @ W_out  (dim order: r, mem(64), enc(64))
#define OFF_C0    12801    // c0 = bv@W_out + b_out
#define OFF_WQC   12832    // wq_all [8][132]: wq[129], c at [129]
#define OFF_MEMA  16384    // memT[64][25000]
#define OFF_MEMB  1616384  // memT[64][25000]
#define OFF_RLAST 3216384  // r_last[25000]
#define OFF_PART  3241384  // partials [8][98][132]: slots 0..128 dims, 129 max, 130 sum
#define NBLK 98
#define PSTRIDE 132

__device__ __forceinline__ float sigm(float x) { return 1.f / (1.f + __expf(-x)); }
__device__ __forceinline__ float tanh_fast(float x) {
  float ax = fabsf(x);
  float e = __expf(-2.f * ax);
  float t = (1.f - e) / (1.f + e);
  return copysignf(t, x);
}
__device__ __forceinline__ float wred_max(float v) {
#pragma unroll
  for (int m = 32; m; m >>= 1) v = fmaxf(v, __shfl_xor(v, m));
  return v;
}
__device__ __forceinline__ float wred_sum(float v) {
#pragma unroll
  for (int m = 32; m; m >>= 1) v += __shfl_xor(v, m);
  return v;
}

// ---------------- setup: fold weights ----------------
__global__ __launch_bounds__(1024) void k_setup(
    const float* __restrict__ W_msg, const float* __restrict__ Wi,
    const float* __restrict__ bi, const float* __restrict__ b_msg,
    const float* __restrict__ Wv, const float* __restrict__ bv,
    const float* __restrict__ W_out, const float* __restrict__ b_out,
    float* __restrict__ ws) {
  int id = blockIdx.x * 1024 + threadIdx.x;
  if (id < 12480) {                       // Wc[k][j] = sum_m W_msg[k][m]*Wi[m][j]
    int k = id / 192, j = id % 192;
    float acc = 0.f;
    for (int m = 0; m < 64; m++) acc += W_msg[k * 64 + m] * Wi[m * 192 + j];
    ws[OFF_WC + id] = acc;
  } else if (id < 12672) {                // bc[j]
    int j = id - 12480;
    float acc = bi[j];
    for (int m = 0; m < 64; m++) acc += b_msg[m] * Wi[m * 192 + j];
    ws[OFF_BC + j] = acc;
  } else if (id < 12801) {                // wvo[d]
    int d = id - 12672;
    float acc = 0.f;
    for (int j = 0; j < 64; j++) acc += Wv[d * 64 + j] * W_out[j];
    ws[OFF_WVO + d] = acc;
  } else if (id == 12801) {               // c0
    float acc = b_out[0];
    for (int j = 0; j < 64; j++) acc += bv[j] * W_out[j];
    ws[OFF_C0] = acc;
  }
}

// ---------------- GRU + fused q-projection ----------------
// 8 waves/block, wave owns 8 l's; lanes = 64 consecutive n; LDS-staged mem/enc.
// After the update, mem_lds holds memNext; the block owning tar_b computes
// wq[129] + c for that b (uniform branch, per-block barriers only).
__global__ __launch_bounds__(512) void k_gru(
    const float* __restrict__ t_in, const float* __restrict__ raw,
    const float* __restrict__ r_last, const float* __restrict__ w_t,
    const float* __restrict__ b_t, const float* __restrict__ bh,
    const float* __restrict__ wc, const float* __restrict__ wh,
    const float* __restrict__ bc, const float* __restrict__ memPrev,
    float* __restrict__ memNext, const int* __restrict__ tar,
    const float* __restrict__ Wq, const float* __restrict__ bq,
    const float* __restrict__ Wk, const float* __restrict__ bk,
    float* __restrict__ wqc, int tt) {
  __shared__ float mem_lds[64][64];
  __shared__ float enc_lds[64][64];
  __shared__ float q_lds[64];
  int tid = threadIdx.x;
  int lane = tid & 63;
  int wv = tid >> 6;
  int n = blockIdx.x * 64 + lane;
  int nc = min(n, NN - 1);

  float tb = t_in[(tt * BB + BB - 1) * NN + nc];
  float rn = (tt == 0) ? raw[(BB - 1) * NN + nc] : r_last[nc];

  // stage: wave wv fills k = wv*8 .. wv*8+7
#pragma unroll
  for (int r = 0; r < 8; r++) {
    int k = wv * 8 + r;
    mem_lds[k][lane] = (tt == 0) ? 0.f : memPrev[k * NN + nc];
    enc_lds[k][lane] = __cosf(tb * w_t[k] + b_t[k]);
  }
  __syncthreads();

  int jb = __builtin_amdgcn_readfirstlane(wv * 8);
  float aR[8], aZ[8], aN[8], hR[8], hZ[8], hN[8];
#pragma unroll
  for (int li = 0; li < 8; li++) {        // biases + r-term (Wc row 0)
    aR[li] = bc[jb + li]        + rn * wc[jb + li];
    aZ[li] = bc[64 + jb + li]   + rn * wc[64 + jb + li];
    aN[li] = bc[128 + jb + li]  + rn * wc[128 + jb + li];
    hR[li] = bh[jb + li];
    hZ[li] = bh[64 + jb + li];
    hN[li] = bh[128 + jb + li];
  }

#pragma unroll 2
  for (int k = 0; k < 64; k++) {
    float ek = enc_lds[k][lane];
    float mk = mem_lds[k][lane];
    const float* wrow = wc + (k + 1) * 192 + jb;   // wave-uniform rows
    const float* hrow = wh + k * 192 + jb;
#pragma unroll
    for (int li = 0; li < 8; li++) {
      aR[li] += ek * wrow[li];
      aZ[li] += ek * wrow[64 + li];
      aN[li] += ek * wrow[128 + li];
      hR[li] += mk * hrow[li];
      hZ[li] += mk * hrow[64 + li];
      hN[li] += mk * hrow[128 + li];
    }
  }

  float newv[8];
#pragma unroll
  for (int li = 0; li < 8; li++) {
    float rg = sigm(aR[li] + hR[li]);
    float zg = sigm(aZ[li] + hZ[li]);
    float ng = tanh_fast(aN[li] + rg * hN[li]);
    newv[li] = (1.f - zg) * ng + zg * mem_lds[jb + li][lane];
  }
  if (n < NN) {
#pragma unroll
    for (int li = 0; li < 8; li++) memNext[(jb + li) * NN + n] = newv[li];
  }
  // mem_lds := memNext for the q-phase
#pragma unroll
  for (int li = 0; li < 8; li++) mem_lds[jb + li][lane] = newv[li];
  __syncthreads();

  // ---- fused q-projection for any b whose tar lands in this block ----
  for (int b = 0; b < BB; b++) {
    int tn = tar[tt * BB + b];                    // block-uniform
    if ((tn >> 6) != (int)blockIdx.x) continue;
    int tl = tn & 63;
    if (tid < 64) {
      float tr = (tt == 0) ? raw[b * NN + tn] : r_last[tn];
      float acc = bq[tid] + tr * Wq[tid];
#pragma unroll 8
      for (int k = 0; k < 64; k++) acc += mem_lds[k][tl] * Wq[(1 + k) * 64 + tid];
#pragma unroll 8
      for (int l = 0; l < 64; l++) acc += __cosf(b_t[l]) * Wq[(65 + l) * 64 + tid];
      q_lds[tid] = acc;
    }
    __syncthreads();
    if (tid < 129) {
      float acc = 0.f;
#pragma unroll 8
      for (int j = 0; j < 64; j++) acc += Wk[tid * 64 + j] * q_lds[j];
      wqc[b * 132 + tid] = acc;
    } else if (tid == 129) {
      float acc = 0.f;
      for (int j = 0; j < 64; j++) acc += bk[j] * q_lds[j];
      wqc[b * 132 + 129] = acc;
    }
    __syncthreads();
  }
}

// ---------------- attention: scores + softmax partials, wave-split phase 2 ----------------
__global__ __launch_bounds__(256) void k_attn(
    const float* __restrict__ t_in, const float* __restrict__ raw,
    const float* __restrict__ r_last, const int* __restrict__ n_mask,
    const float* __restrict__ w_t, const float* __restrict__ b_t,
    const float* __restrict__ wqc, const float* __restrict__ mem2,
    float* __restrict__ part, int tt) {
  __shared__ float wq_lds[132];
  __shared__ float e_sh[256], t_sh[256];
  __shared__ float red4[4], redS[4], redR[4];
  __shared__ float pm[2][64], pe[2][64];

  int tid = threadIdx.x;
  int lane = tid & 63;
  int wvid = tid >> 6;
  int b = blockIdx.y;
  int n0 = blockIdx.x * 256;
  int n = n0 + tid;
  int nc = min(n, NN - 1);
  bool valid = (n < NN);

  if (tid < 132) wq_lds[tid] = wqc[b * 132 + tid];

  float tb = t_in[(tt * BB + b) * NN + nc];
  int mk = n_mask[(tt * BB + b) * NN + nc];
  float rn = (tt == 0) ? raw[b * NN + nc] : r_last[nc];
  __syncthreads();

  // score
  float sc = rn * wq_lds[0];
#pragma unroll 8
  for (int d = 0; d < 64; d++) sc += mem2[d * NN + nc] * wq_lds[1 + d];
#pragma unroll 8
  for (int l = 0; l < 64; l++) sc += __cosf(tb * w_t[l] + b_t[l]) * wq_lds[65 + l];
  float score = (sc + wq_lds[129]) * 0.125f;
  bool act = valid && (mk > 0);

  float mw = wred_max(act ? score : -1e30f);
  if (lane == 0) red4[wvid] = mw;
  __syncthreads();
  float mb = fmaxf(fmaxf(red4[0], red4[1]), fmaxf(red4[2], red4[3]));

  float e = act ? __expf(score - mb) : 0.f;
  float sw = wred_sum(e);
  float sr = wred_sum(e * rn);
  if (lane == 0) { redS[wvid] = sw; redR[wvid] = sr; }
  e_sh[tid] = e;
  t_sh[tid] = tb;
  __syncthreads();
  float Sb = redS[0] + redS[1] + redS[2] + redS[3];
  float Rb = redR[0] + redR[1] + redR[2] + redR[3];

  // phase 2: waves 0/1 -> mem dims, waves 2/3 -> enc dims
  if (wvid < 2) {
    const float* mrow = mem2 + lane * NN + n0;
    int i0 = wvid * 128;
    float acc = 0.f;
#pragma unroll 4
    for (int i = i0; i < i0 + 128; i++) acc += e_sh[i] * mrow[i];
    pm[wvid][lane] = acc;
  } else {
    float wl = w_t[lane], bl = b_t[lane];
    int i0 = (wvid - 2) * 128;
    float acc = 0.f;
#pragma unroll 4
    for (int i = i0; i < i0 + 128; i++) acc += e_sh[i] * __cosf(t_sh[i] * wl + bl);
    pe[wvid - 2][lane] = acc;
  }
  __syncthreads();

  int pbase = (b * NBLK + blockIdx.x) * PSTRIDE;
  if (tid < 64) part[pbase + 1 + tid] = pm[0][tid] + pm[1][tid];
  else if (tid < 128) part[pbase + 65 + (tid - 64)] = pe[0][tid - 64] + pe[1][tid - 64];
  else if (tid == 128) part[pbase + 0] = Rb;
  else if (tid == 129) part[pbase + 129] = mb;
  else if (tid == 130) part[pbase + 130] = Sb;
}

// ---------------- merge: blocks 0..97 r_last blend (skip tars); 98..105 logits ----------------
__global__ __launch_bounds__(256) void k_merge(
    const float* __restrict__ part, const float* __restrict__ wvo,
    const float* __restrict__ c0p, const int* __restrict__ tar,
    const float* __restrict__ raw, const float* __restrict__ r_label,
    float* __restrict__ r_last, float* __restrict__ out, int tt) {
  int tid = threadIdx.x;
  if (blockIdx.x < NBLK) {
    int n = blockIdx.x * 256 + tid;
    if (n >= NN) return;
    bool istar = false;
#pragma unroll
    for (int b = 0; b < BB; b++) istar |= (tar[tt * BB + b] == n);
    if (istar) return;
    float base = (tt == 0) ? raw[(BB - 1) * NN + n] : r_last[n];
    r_last[n] = 0.5f * (base + r_label[(tt * BB + BB - 1) * NN + n]);
    return;
  }

  int b = blockIdx.x - NBLK;
  const float* pb = part + b * NBLK * PSTRIDE;
  __shared__ float red[256], fac[NBLK];

  red[tid] = (tid < NBLK) ? pb[tid * PSTRIDE + 129] : -1e30f;
  __syncthreads();
  for (int s = 128; s > 0; s >>= 1) {
    if (tid < s) red[tid] = fmaxf(red[tid], red[tid + s]);
    __syncthreads();
  }
  float mb = red[0];
  __syncthreads();
  if (tid < NBLK) fac[tid] = __expf(pb[tid * PSTRIDE + 129] - mb);
  __syncthreads();
  red[tid] = (tid < NBLK) ? pb[tid * PSTRIDE + 130] * fac[tid] : 0.f;
  __syncthreads();
  for (int s = 128; s > 0; s >>= 1) {
    if (tid < s) red[tid] += red[tid + s];
    __syncthreads();
  }
  float Sb = red[0];
  __syncthreads();

  float acc = 0.f;
  if (tid < DIN) {
    for (int j = 0; j < NBLK; j++) acc += fac[j] * pb[j * PSTRIDE + tid];
    acc *= wvo[tid];
  }
  red[tid] = (tid < DIN) ? acc : 0.f;
  __syncthreads();
  for (int s = 128; s > 0; s >>= 1) {
    if (tid < s) red[tid] += red[tid + s];
    __syncthreads();
  }
  if (tid == 0) {
    float lg = red[0] / Sb + c0p[0];
    out[tt * BB + b] = lg;
    int mytar = tar[tt * BB + b];
    bool last = true;
    for (int bb = b + 1; bb < BB; bb++)
      if (tar[tt * BB + bb] == mytar) last = false;
    if (last)
      r_last[mytar] = 0.5f * (lg + r_label[(tt * BB + BB - 1) * NN + mytar]);
  }
}

extern "C" void kernel_launch(void* const* d_in, const int* in_sizes, int n_in,
                              void* d_out, int out_size, void* d_ws, size_t ws_size,
                              hipStream_t stream) {
  const float* raw     = (const float*)d_in[0];
  const float* r_label = (const float*)d_in[1];
  const float* t_in    = (const float*)d_in[2];
  const int*   tar     = (const int*)d_in[4];
  const int*   n_mask  = (const int*)d_in[5];
  const float* w_t     = (const float*)d_in[6];
  const float* b_t     = (const float*)d_in[7];
  const float* W_msg   = (const float*)d_in[8];
  const float* b_msg   = (const float*)d_in[9];
  const float* Wi      = (const float*)d_in[10];
  const float* Wh      = (const float*)d_in[11];
  const float* bi      = (const float*)d_in[12];
  const float* bh      = (const float*)d_in[13];
  const float* Wq      = (const float*)d_in[14];
  const float* bq      = (const float*)d_in[15];
  const float* Wk      = (const float*)d_in[16];
  const float* bk      = (const float*)d_in[17];
  const float* Wv      = (const float*)d_in[18];
  const float* bv      = (const float*)d_in[19];
  const float* W_out   = (const float*)d_in[20];
  const float* b_out   = (const float*)d_in[21];

  float* ws  = (float*)d_ws;
  float* out = (float*)d_out;

  k_setup<<<13, 1024, 0, stream>>>(W_msg, Wi, bi, b_msg, Wv, bv, W_out, b_out, ws);

  for (int tt = 0; tt < TSTEPS; tt++) {
    float* mp = ws + ((tt & 1) ? OFF_MEMB : OFF_MEMA);
    float* mn = ws + ((tt & 1) ? OFF_MEMA : OFF_MEMB);
    k_gru<<<dim3((NN + 63) / 64), dim3(512), 0, stream>>>(
        t_in, raw, ws + OFF_RLAST, w_t, b_t, bh,
        ws + OFF_WC, Wh, ws + OFF_BC, mp, mn,
        tar, Wq, bq, Wk, bk, ws + OFF_WQC, tt);
    k_attn<<<dim3(NBLK, BB), dim3(256), 0, stream>>>(
        t_in, raw, ws + OFF_RLAST, n_mask, w_t, b_t,
        ws + OFF_WQC, mn, ws + OFF_PART, tt);
    k_merge<<<dim3(NBLK + BB), dim3(256), 0, stream>>>(
        ws + OFF_PART, ws + OFF_WVO, ws + OFF_C0, tar,
        raw, r_label, ws + OFF_RLAST, out, tt);
  }
}